// Round 5
// baseline (132.446 us; speedup 1.0000x reference)
//
#include <hip/hip_runtime.h>

// Problem constants (fixed by the reference):
//   N=20000 nodes, E=640000 edges, FIN=128, FTOT=384 (q|k|v each 128), H=8, FH=16
constexpr int FIN = 128;

// Fixed softmax-shift: xm enters only via eps' = 1e-8*exp(xm); fixed 8.0 vs the
// true global max (~5.3) perturbs attn by ~1e-4 — enables one-pass attention.
constexpr float XM0 = 8.0f;

typedef __attribute__((ext_vector_type(8))) short bf8x;            // 8 bf16 (MFMA A/B frag)
typedef __attribute__((ext_vector_type(8))) unsigned short u16x8;  // 8 bf16 raw
typedef __attribute__((ext_vector_type(4))) float f4x;             // MFMA C/D frag

__device__ inline unsigned short f2bf(float v) {  // RNE float->bf16 bits
  unsigned int u = __float_as_uint(v);
  unsigned int r = u + 0x7FFFu + ((u >> 16) & 1u);
  return (unsigned short)(r >> 16);
}
__device__ inline float bf2f(unsigned short s) {
  return __uint_as_float(((unsigned int)s) << 16);
}

// ---------------------------------------------------------------------------
// K1: proj = x @ W^T via split-bf16 MFMA (hi*hi + hi*lo + lo*hi ~ fp32).
// Block 256 thr = 2x2 waves; block tile 128x128; wave tile 64x64 = 4x4 mfma
// 16x16x32 tiles. K staged in two 64-panels (74 KB LDS -> 2 blocks/CU).
// Outputs: qbuf fp32 [N,128] (x0.25), kv bf16-bits [N,256].
// FUSED: first 20001 global threads also compute CSR row_ptr (binary search
// over sorted src) — saves a kernel launch; latency hides under staging.
// ---------------------------------------------------------------------------
__global__ __launch_bounds__(256, 2) void proj_kernel(
    const float* __restrict__ x, const float* __restrict__ W,
    float* __restrict__ qbuf, unsigned short* __restrict__ kv, int N,
    const int* __restrict__ src, int* __restrict__ row_ptr, int E) {
  __shared__ unsigned short xhi[128][72], xlo[128][72];   // row-major [row][k], pad->72
  __shared__ unsigned short whi[128][72], wlo[128][72];   // [out-col][k]

  const int tid = threadIdx.x;
  const int r0 = blockIdx.y * 128;
  const int c0 = blockIdx.x * 128;   // 0:q, 128:k, 256:v

  // ---- fused row_ptr build (blocks with low linear id only) ----
  {
    const int gid = (blockIdx.y * gridDim.x + blockIdx.x) * 256 + tid;
    if (gid <= N) {
      int lo = 0, hi = E;
      while (lo < hi) {
        int mid = (lo + hi) >> 1;
        if (src[mid] < gid) lo = mid + 1; else hi = mid;
      }
      row_ptr[gid] = lo;
    }
  }

  const int lane = tid & 63;
  const int w = tid >> 6;
  const int mbase = (w >> 1) * 64;
  const int nbase = (w & 1) * 64;
  const int lr = lane & 15;          // A-row / B-col / D-col within 16-tile
  const int q4 = lane >> 4;          // quad: k-offset q4*8; D-row q4*4+rr

  f4x acc[4][4];
#pragma unroll
  for (int mt = 0; mt < 4; ++mt)
#pragma unroll
    for (int nt = 0; nt < 4; ++nt)
#pragma unroll
      for (int k = 0; k < 4; ++k) acc[mt][nt][k] = 0.f;

  for (int p = 0; p < 2; ++p) {      // two K-panels of 64
    if (p) __syncthreads();          // compute of prev panel done before restage
    // stage panel: 128 rows x 16 float4 each for x and W, with hi/lo split
#pragma unroll
    for (int pass = 0; pass < 8; ++pass) {
      const int idx = tid + pass * 256;
      const int kq = idx & 15, r = idx >> 4;
      float4 xv = make_float4(0.f, 0.f, 0.f, 0.f);
      if (r0 + r < N) xv = *(const float4*)(x + (size_t)(r0 + r) * FIN + p * 64 + kq * 4);
      const float4 wv = *(const float4*)(W + (size_t)(c0 + r) * FIN + p * 64 + kq * 4);
      const float xa[4] = {xv.x, xv.y, xv.z, xv.w};
      const float wa[4] = {wv.x, wv.y, wv.z, wv.w};
      unsigned short xh[4], xl[4], wh[4], wl[4];
#pragma unroll
      for (int i = 0; i < 4; ++i) {
        xh[i] = f2bf(xa[i]); xl[i] = f2bf(xa[i] - bf2f(xh[i]));
        wh[i] = f2bf(wa[i]); wl[i] = f2bf(wa[i] - bf2f(wh[i]));
      }
      *(ushort4*)&xhi[r][kq * 4] = make_ushort4(xh[0], xh[1], xh[2], xh[3]);
      *(ushort4*)&xlo[r][kq * 4] = make_ushort4(xl[0], xl[1], xl[2], xl[3]);
      *(ushort4*)&whi[r][kq * 4] = make_ushort4(wh[0], wh[1], wh[2], wh[3]);
      *(ushort4*)&wlo[r][kq * 4] = make_ushort4(wl[0], wl[1], wl[2], wl[3]);
    }
    __syncthreads();

#pragma unroll
    for (int kit = 0; kit < 2; ++kit) {   // K=32 per mfma
      const int ko = kit * 32 + q4 * 8;
      bf8x ah[4], al[4], bh[4], bl[4];
#pragma unroll
      for (int i2 = 0; i2 < 4; ++i2) {
        ah[i2] = *(const bf8x*)&xhi[mbase + i2 * 16 + lr][ko];
        al[i2] = *(const bf8x*)&xlo[mbase + i2 * 16 + lr][ko];
        bh[i2] = *(const bf8x*)&whi[nbase + i2 * 16 + lr][ko];
        bl[i2] = *(const bf8x*)&wlo[nbase + i2 * 16 + lr][ko];
      }
#pragma unroll
      for (int mt = 0; mt < 4; ++mt)
#pragma unroll
        for (int nt = 0; nt < 4; ++nt) {
          acc[mt][nt] = __builtin_amdgcn_mfma_f32_16x16x32_bf16(ah[mt], bh[nt], acc[mt][nt], 0, 0, 0);
          acc[mt][nt] = __builtin_amdgcn_mfma_f32_16x16x32_bf16(ah[mt], bl[nt], acc[mt][nt], 0, 0, 0);
          acc[mt][nt] = __builtin_amdgcn_mfma_f32_16x16x32_bf16(al[mt], bh[nt], acc[mt][nt], 0, 0, 0);
        }
    }
  }

  // epilogue: C/D layout col=lane&15, row=quad*4+reg  [m89-verified]
#pragma unroll
  for (int mt = 0; mt < 4; ++mt)
#pragma unroll
    for (int nt = 0; nt < 4; ++nt)
#pragma unroll
      for (int rr = 0; rr < 4; ++rr) {
        const int row = r0 + mbase + mt * 16 + q4 * 4 + rr;
        if (row < N) {
          const int c = c0 + nbase + nt * 16 + lr;
          const float v = acc[mt][nt][rr];
          if (c < 128) qbuf[(size_t)row * 128 + c] = v * 0.25f;       // q * FH^-0.5
          else kv[(size_t)row * 256 + (c - 128)] = f2bf(v);           // k|v bf16
        }
      }
}

// ---------------------------------------------------------------------------
// K2: wave-per-node one-pass attention. ZERO barriers, ZERO LDS.
// One 64-lane wave handles one node (4 nodes per 256-thread block). Chunk =
// 16 edges:
//   dot role   (sd=lane>>3 in [0,8), hd=lane&7): edges ce+sd, ce+sd+8; each
//              lane computes its head's FULL 16-wide dot in registers (q held
//              in 16 VGPRs) -> exp -> aA,aB. esum accumulated here too.
//   accum role (oc=lane&15, sa=lane>>4 in [0,4)): edges ce+sa+{0,4,8,12};
//              v via b128 loads; attn weights fetched from dot lanes with 4
//              __shfl (ds_bpermute — wave-synchronous, no barrier).
// OOB edges: clamp index (loads stay valid), zero the attn weight.
// End of node: acc8 reduced across slots via shfl_xor(16,32); esum via
// shfl_xor(8,16,32); 32 lanes store 16B each (contiguous 512 B row).
// ---------------------------------------------------------------------------
__global__ __launch_bounds__(256, 4) void attn_kernel(
    const float* __restrict__ qbuf, const unsigned short* __restrict__ kv,
    const int* __restrict__ dest, const int* __restrict__ row_ptr,
    float* __restrict__ out, int N) {
  const int lane = threadIdx.x & 63;
  const int n = blockIdx.x * 4 + (threadIdx.x >> 6);
  if (n >= N) return;

  const int e0 = row_ptr[n], e1 = row_ptr[n + 1];

  const int hd = lane & 7, sd = lane >> 3;   // dot role
  const int oc = lane & 15, sa = lane >> 4;  // accum role
  const int ha = oc >> 1;                    // accum lane's head

  // q for head hd, 16 fp32 regs
  float q[16];
  {
    const float* qp = qbuf + (size_t)n * 128 + hd * 16;
#pragma unroll
    for (int j4 = 0; j4 < 4; ++j4) {
      const float4 qv = *(const float4*)(qp + j4 * 4);
      q[j4 * 4 + 0] = qv.x; q[j4 * 4 + 1] = qv.y;
      q[j4 * 4 + 2] = qv.z; q[j4 * 4 + 3] = qv.w;
    }
  }

  float acc8[8];
#pragma unroll
  for (int j = 0; j < 8; ++j) acc8[j] = 0.f;
  float es_d = 0.f;  // per-(sd,hd) esum partial, accumulated at dot lanes

  for (int ce = e0; ce < e1; ce += 16) {
    // ---- dot role: edges eA=ce+sd, eB=ce+sd+8 (clamped) ----
    const int eA = ce + sd, eB = ce + sd + 8;
    const int cA = (eA < e1) ? eA : e1 - 1;
    const int cB = (eB < e1) ? eB : e1 - 1;
    const int dA = dest[cA];
    const int dB = dest[cB];
    const u16x8* kA = (const u16x8*)(kv + (size_t)dA * 256 + hd * 16);
    const u16x8* kB = (const u16x8*)(kv + (size_t)dB * 256 + hd * 16);
    const u16x8 kA0 = kA[0], kA1 = kA[1], kB0 = kB[0], kB1 = kB[1];

    // ---- accum role: v loads for edges ce+sa+{0,4,8,12} (clamped) ----
    const int i0 = ce + sa, i1 = ce + sa + 4, i2 = ce + sa + 8, i3 = ce + sa + 12;
    const int c0i = (i0 < e1) ? i0 : e1 - 1;
    const int c1i = (i1 < e1) ? i1 : e1 - 1;
    const int c2i = (i2 < e1) ? i2 : e1 - 1;
    const int c3i = (i3 < e1) ? i3 : e1 - 1;
    const u16x8 v0 = *(const u16x8*)(kv + (size_t)dest[c0i] * 256 + 128 + oc * 8);
    const u16x8 v1 = *(const u16x8*)(kv + (size_t)dest[c1i] * 256 + 128 + oc * 8);
    const u16x8 v2 = *(const u16x8*)(kv + (size_t)dest[c2i] * 256 + 128 + oc * 8);
    const u16x8 v3 = *(const u16x8*)(kv + (size_t)dest[c3i] * 256 + 128 + oc * 8);

    // ---- dots + exp ----
    float sA = 0.f, sB = 0.f;
#pragma unroll
    for (int jj = 0; jj < 8; ++jj) sA += q[jj] * bf2f(kA0[jj]);
#pragma unroll
    for (int jj = 0; jj < 8; ++jj) sA += q[8 + jj] * bf2f(kA1[jj]);
#pragma unroll
    for (int jj = 0; jj < 8; ++jj) sB += q[jj] * bf2f(kB0[jj]);
#pragma unroll
    for (int jj = 0; jj < 8; ++jj) sB += q[8 + jj] * bf2f(kB1[jj]);
    const float aA = (eA < e1) ? (__expf(sA - XM0) + 1e-8f) : 0.f;
    const float aB = (eB < e1) ? (__expf(sB - XM0) + 1e-8f) : 0.f;
    es_d += aA + aB;

    // ---- pass attn weights to accum lanes (wave-synchronous shuffles) ----
    const int l0 = sa * 8 + ha;          // lane holding attn(edge ce+sa,   ha)
    const int l1 = l0 + 32;              // lane holding attn(edge ce+sa+4, ha)
    const float a0 = __shfl(aA, l0);
    const float a1 = __shfl(aA, l1);
    const float a2 = __shfl(aB, l0);     // edge ce+sa+8
    const float a3 = __shfl(aB, l1);     // edge ce+sa+12

    // ---- weighted v accumulate (OOB edges have a==0) ----
#pragma unroll
    for (int jj = 0; jj < 8; ++jj)
      acc8[jj] += a0 * bf2f(v0[jj]) + a1 * bf2f(v1[jj]) +
                  a2 * bf2f(v2[jj]) + a3 * bf2f(v3[jj]);
  }

  // ---- end-of-node reductions (all shfl, no LDS) ----
#pragma unroll
  for (int jj = 0; jj < 8; ++jj) {
    acc8[jj] += __shfl_xor(acc8[jj], 16);
    acc8[jj] += __shfl_xor(acc8[jj], 32);   // all 4 slot-lanes now hold full sum
  }
  es_d += __shfl_xor(es_d, 8);
  es_d += __shfl_xor(es_d, 16);
  es_d += __shfl_xor(es_d, 32);             // lane now holds es_tot for head (lane&7)
  const float es = __shfl(es_d, ha);        // es_tot for this accum lane's head
  const float inv = (e1 > e0) ? (1.0f / es) : 0.f;

  float* op = out + (size_t)n * 128 + oc * 8;
  if (sa == 0)
    *(float4*)op = make_float4(acc8[0] * inv, acc8[1] * inv, acc8[2] * inv, acc8[3] * inv);
  else if (sa == 1)
    *(float4*)(op + 4) = make_float4(acc8[4] * inv, acc8[5] * inv, acc8[6] * inv, acc8[7] * inv);
}

// ---------------------------------------------------------------------------
extern "C" void kernel_launch(void* const* d_in, const int* in_sizes, int n_in,
                              void* d_out, int out_size, void* d_ws, size_t ws_size,
                              hipStream_t stream) {
  const float* x = (const float*)d_in[0];
  const float* W = (const float*)d_in[1];
  // d_in[2] = batch (unused by the reference computation)
  const int* ei = (const int*)d_in[3];

  const int N = in_sizes[0] / FIN;  // 20000
  const int E = in_sizes[3] / 2;    // 640000
  const int* src = ei;
  const int* dst = ei + E;
  float* out = (float*)d_out;

  // workspace: qbuf fp32 [N,128] | kv bf16-bits [N,256] | row_ptr [N+1]
  char* ws = (char*)d_ws;
  float* qbuf = (float*)ws;
  size_t off = (size_t)N * 128 * sizeof(float);
  unsigned short* kvb = (unsigned short*)(ws + off);
  off += (size_t)N * 256 * sizeof(unsigned short);
  int* row_ptr = (int*)(ws + off);

  dim3 pgrid(3, (N + 127) / 128);
  proj_kernel<<<pgrid, 256, 0, stream>>>(x, W, qbuf, kvb, N, src, row_ptr, E);
  attn_kernel<<<(N + 3) / 4, 256, 0, stream>>>(qbuf, kvb, dst, row_ptr, out, N);
}